// Round 5
// baseline (4102.304 us; speedup 1.0000x reference)
//
#include <hip/hip_runtime.h>
#include <hip/hip_cooperative_groups.h>
#include <math.h>

namespace cg = cooperative_groups;

#define SDIM 2048
#define BATCH 1024
#define NITER 16
#define LM 96   // Lanczos steps

typedef unsigned short ushort_t;
typedef __attribute__((ext_vector_type(8))) short bf16x8;
typedef __attribute__((ext_vector_type(4))) float f32x4;

#define MFMA(a,b,c) __builtin_amdgcn_mfma_f32_16x16x32_bf16((a),(b),(c),0,0,0)

__device__ __forceinline__ float softt(float v, float th){
  return copysignf(fmaxf(fabsf(v) - th, 0.0f), v);
}

__device__ __forceinline__ float bf2f(ushort_t h){
  return __uint_as_float(((unsigned)h) << 16);
}

// RTNE float -> bf16 hi + bf16 lo split
__device__ __forceinline__ void split2(float x, ushort_t* h, ushort_t* l){
  unsigned u = __float_as_uint(x);
  unsigned hh = (u + 0x7FFFu + ((u >> 16) & 1u)) >> 16;
  float hf = __uint_as_float(hh << 16);
  float r = x - hf;                       // exact
  unsigned v = __float_as_uint(r);
  unsigned ll = (v + 0x7FFFu + ((v >> 16) & 1u)) >> 16;
  *h = (ushort_t)hh; *l = (ushort_t)ll;
}

// async 16B global -> LDS
__device__ __forceinline__ void cp16(const ushort_t* g, ushort_t* l){
  __builtin_amdgcn_global_load_lds(
      (const __attribute__((address_space(1))) unsigned int*)g,
      (__attribute__((address_space(3))) unsigned int*)l, 16, 0, 0);
}

// ---------------- MFMA GEMM core (round-3 proven version, BK=64) ----------------
// C[m][n] = sum_k A[m][k]*B[n][k], A,B row-major bf16 hi/lo split.
// 64x64 tile, BK=64, 256 threads = 4 waves of 32x32 output each.
// LDS: chunk (row r, kchunk kp of 8) at ushort offset r*64 + (kp^(r&7))*8 —
// lane-linear for cp16 AND measured 0 bank conflicts on ds_read_b128.
__device__ __forceinline__ void gemm_core(const ushort_t* __restrict__ Ah, const ushort_t* __restrict__ Al,
                                          const ushort_t* __restrict__ Bh, const ushort_t* __restrict__ Bl,
                                          int m0, int n0, int K, f32x4 acc[2][2])
{
  __shared__ ushort_t lAh[64*64], lAl[64*64], lBh[64*64], lBl[64*64];
  const int tid = threadIdx.x;
  const int rr = tid >> 3;
  const int kp = (tid & 7) ^ (rr & 7);
  const size_t strA = (size_t)32 * K;
  const ushort_t* gAh = Ah + (size_t)(m0 + rr) * K + kp * 8;
  const ushort_t* gAl = Al + (size_t)(m0 + rr) * K + kp * 8;
  const ushort_t* gBh = Bh + (size_t)(n0 + rr) * K + kp * 8;
  const ushort_t* gBl = Bl + (size_t)(n0 + rr) * K + kp * 8;
  ushort_t* dA0 = &lAh[tid * 8];      ushort_t* dA1 = &lAh[(tid + 256) * 8];
  ushort_t* dAl0 = &lAl[tid * 8];     ushort_t* dAl1 = &lAl[(tid + 256) * 8];
  ushort_t* dB0 = &lBh[tid * 8];      ushort_t* dB1 = &lBh[(tid + 256) * 8];
  ushort_t* dBl0 = &lBl[tid * 8];     ushort_t* dBl1 = &lBl[(tid + 256) * 8];

  const int lane = tid & 63, wv = tid >> 6;
  const int wm = (wv >> 1) * 32, wn = (wv & 1) * 32;
  const int mm = lane & 15, quad = lane >> 4;
  const int ra0 = wm + mm, ra1 = wm + 16 + mm;
  const int rb0 = wn + mm, rb1 = wn + 16 + mm;

  const int nk = K / 64;
  for (int kt = 0; kt < nk; kt++){
    cp16(gAh, dA0); cp16(gAh + strA, dA1);
    cp16(gAl, dAl0); cp16(gAl + strA, dAl1);
    cp16(gBh, dB0); cp16(gBh + strA, dB1);
    cp16(gBl, dBl0); cp16(gBl + strA, dBl1);
    gAh += 64; gAl += 64; gBh += 64; gBl += 64;
    __syncthreads();   // drains vmcnt -> staged tile visible
    #pragma unroll
    for (int u = 0; u < 2; u++){
      const int oa0 = ra0*64 + (((u*4 + quad) ^ (ra0 & 7)) << 3);
      const int oa1 = ra1*64 + (((u*4 + quad) ^ (ra1 & 7)) << 3);
      const int ob0 = rb0*64 + (((u*4 + quad) ^ (rb0 & 7)) << 3);
      const int ob1 = rb1*64 + (((u*4 + quad) ^ (rb1 & 7)) << 3);
      bf16x8 ah0 = *(const bf16x8*)&lAh[oa0];
      bf16x8 ah1 = *(const bf16x8*)&lAh[oa1];
      bf16x8 al0 = *(const bf16x8*)&lAl[oa0];
      bf16x8 al1 = *(const bf16x8*)&lAl[oa1];
      bf16x8 bh0 = *(const bf16x8*)&lBh[ob0];
      bf16x8 bh1 = *(const bf16x8*)&lBh[ob1];
      bf16x8 bl0 = *(const bf16x8*)&lBl[ob0];
      bf16x8 bl1 = *(const bf16x8*)&lBl[ob1];
      acc[0][0] = MFMA(ah0, bh0, acc[0][0]);
      acc[0][0] = MFMA(ah0, bl0, acc[0][0]);
      acc[0][0] = MFMA(al0, bh0, acc[0][0]);
      acc[0][1] = MFMA(ah0, bh1, acc[0][1]);
      acc[0][1] = MFMA(ah0, bl1, acc[0][1]);
      acc[0][1] = MFMA(al0, bh1, acc[0][1]);
      acc[1][0] = MFMA(ah1, bh0, acc[1][0]);
      acc[1][0] = MFMA(ah1, bl0, acc[1][0]);
      acc[1][0] = MFMA(al1, bh0, acc[1][0]);
      acc[1][1] = MFMA(ah1, bh1, acc[1][1]);
      acc[1][1] = MFMA(ah1, bl1, acc[1][1]);
      acc[1][1] = MFMA(al1, bh1, acc[1][1]);
    }
    __syncthreads();   // protect LDS before next stage
  }
}

// ---------------- W split / transpose-split ----------------
__global__ __launch_bounds__(256) void k_split(const float* __restrict__ W,
                                               ushort_t* __restrict__ Wah, ushort_t* __restrict__ Wal,
                                               ushort_t* __restrict__ Wbh, ushort_t* __restrict__ Wbl){
  __shared__ float t[32][33];
  const int i0 = blockIdx.y * 32, j0 = blockIdx.x * 32;
  const int r = threadIdx.x >> 3, c = (threadIdx.x & 7) * 4;
  const float4 v = *(const float4*)&W[(size_t)(i0 + r) * SDIM + j0 + c];
  float vv[4] = {v.x, v.y, v.z, v.w};
  ushort_t h[4], l[4];
  #pragma unroll
  for (int q = 0; q < 4; q++){ split2(vv[q], &h[q], &l[q]); t[r][c+q] = vv[q]; }
  *(ushort4*)&Wah[(size_t)(i0 + r) * SDIM + j0 + c] = make_ushort4(h[0],h[1],h[2],h[3]);
  *(ushort4*)&Wal[(size_t)(i0 + r) * SDIM + j0 + c] = make_ushort4(l[0],l[1],l[2],l[3]);
  __syncthreads();
  #pragma unroll
  for (int q = 0; q < 4; q++) split2(t[c+q][r], &h[q], &l[q]);
  *(ushort4*)&Wbh[(size_t)(j0 + r) * SDIM + i0 + c] = make_ushort4(h[0],h[1],h[2],h[3]);
  *(ushort4*)&Wbl[(size_t)(j0 + r) * SDIM + i0 + c] = make_ushort4(l[0],l[1],l[2],l[3]);
}

// M = W * W^T (same nonzero spectrum as W^T W)
__global__ __launch_bounds__(256) void k_gemmM(const ushort_t* __restrict__ Wah, const ushort_t* __restrict__ Wal,
                                               float* __restrict__ Mmat){
  f32x4 acc[2][2] = {};
  const int m0 = blockIdx.y * 64, n0 = blockIdx.x * 64;
  gemm_core(Wah, Wal, Wah, Wal, m0, n0, SDIM, acc);
  const int tid = threadIdx.x, lane = tid & 63, wv = tid >> 6;
  const int wm = (wv >> 1) * 32, wn = (wv & 1) * 32;
  const int mm = lane & 15, quad = lane >> 4;
  #pragma unroll
  for (int tm = 0; tm < 2; tm++)
    #pragma unroll
    for (int tn = 0; tn < 2; tn++)
      #pragma unroll
      for (int i = 0; i < 4; i++){
        int row = m0 + wm + tm*16 + quad*4 + i;
        int col = n0 + wn + tn*16 + mm;
        Mmat[(size_t)row * SDIM + col] = acc[tm][tn][i];
      }
}

// ---------------- Fused Lanczos: init + LM steps + Sturm, one cooperative kernel ----------------
// 256 blocks x 256 threads (1 block/CU, co-resident). Each block: 8 rows of M.
// Step: redundant per-block v-reconstruction (fp64 scalar chain via
// beta^2_{s-1} = ||w||^2 - alpha^2 - beta^2_{s-2}), matvec from L2-resident M,
// per-block double atomicAdd of dot(w,v), dot(w,w). grid.sync() between steps.
__global__ __launch_bounds__(256) void k_lanczos(
    const float* __restrict__ M, float* __restrict__ w0, float* __restrict__ w1,
    float* __restrict__ vRing, double* __restrict__ dotWV, double* __restrict__ dotWW,
    float* __restrict__ betaSq, const float* __restrict__ alphaIn, float* __restrict__ Lbuf)
{
  cg::grid_group gridg = cg::this_grid();
  __shared__ float vs[SDIM];
  __shared__ double pAl[4], pWw[4];
  __shared__ float red[256];
  __shared__ double sa[LM+1], sb[LM+1];
  const int tid = threadIdx.x, bid = blockIdx.x;

  // ---- init: deterministic v1 (identical in every block) ----
  {
    float vals[8]; float s = 0.f;
    #pragma unroll
    for (int p = 0; p < 8; p++){
      int j = p*256 + tid;
      unsigned h = (unsigned)j * 2654435761u;
      h ^= h >> 16; h *= 2246822519u; h ^= h >> 13;
      float r = (float)(h & 0xFFFFFFu) / 16777216.0f - 0.5f;
      vals[p] = r; s += r*r;
    }
    red[tid] = s; __syncthreads();
    for (int o = 128; o > 0; o >>= 1){ if (tid < o) red[tid] += red[tid+o]; __syncthreads(); }
    float inv = rsqrtf(red[0]);
    #pragma unroll
    for (int p = 0; p < 8; p++){ int j = p*256 + tid; vs[j] = vals[p]*inv; }
    if (bid == 0){
      #pragma unroll
      for (int p = 0; p < 8; p++){
        int j = p*256 + tid;
        vRing[SDIM + j] = vs[j];     // slot 1 = v_1
        vRing[j] = 0.f;              // slot 0
        vRing[2*SDIM + j] = 0.f;     // slot 2
      }
      if (tid < LM+2){ dotWV[tid] = 0.0; dotWW[tid] = 0.0; betaSq[tid] = 0.f; }
    }
  }
  __syncthreads();
  gridg.sync();   // zeroed accumulators + vRing visible everywhere

  for (int s = 1; s <= LM; s++){
    if (s > 1){
      const double a  = dotWV[s-1];
      const double ww = dotWW[s-1];
      const float bpSq = betaSq[s-2];
      float bsq = (float)(ww - a*a - (double)bpSq);
      bsq = fmaxf(bsq, 1e-20f);
      const float beta = sqrtf(bsq), invb = 1.0f/beta;
      const float alphaS = (float)a, bprev = sqrtf(bpSq);
      const float* wOld = (s & 1) ? w1 : w0;   // w_{s-1}
      const float* vm1 = vRing + ((s-1)%3)*SDIM;
      const float* vm2 = vRing + ((s-2)%3)*SDIM;
      float* vdst = vRing + (s%3)*SDIM;
      for (int j = tid; j < SDIM; j += 256){
        float val = (wOld[j] - alphaS*vm1[j] - bprev*vm2[j]) * invb;
        vs[j] = val;
        if (bid == 0) vdst[j] = val;
      }
      if (bid == 0 && tid == 0) betaSq[s-1] = bsq;
    }
    __syncthreads();
    // matvec: 8 rows per block, 2 per wave
    const int wv = tid >> 6, lane = tid & 63;
    float* wNew = (s & 1) ? w0 : w1;   // w_s
    double aw = 0.0, ww2 = 0.0;
    #pragma unroll
    for (int rl = 0; rl < 2; rl++){
      const int row = bid*8 + wv*2 + rl;
      const float4* Mr = (const float4*)(M + (size_t)row * SDIM);
      const float4* v4 = (const float4*)vs;
      float acc = 0.f;
      #pragma unroll
      for (int p = 0; p < 8; p++){
        int j4 = p*64 + lane;
        float4 m = Mr[j4], v = v4[j4];
        acc += m.x*v.x + m.y*v.y + m.z*v.z + m.w*v.w;
      }
      #pragma unroll
      for (int o = 32; o > 0; o >>= 1) acc += __shfl_down(acc, o);
      if (lane == 0){
        wNew[row] = acc;
        aw  += (double)acc * (double)vs[row];
        ww2 += (double)acc * (double)acc;
      }
    }
    if (lane == 0){ pAl[wv] = aw; pWw[wv] = ww2; }
    __syncthreads();
    if (tid == 0){
      atomicAdd(&dotWV[s], pAl[0]+pAl[1]+pAl[2]+pAl[3]);
      atomicAdd(&dotWW[s], pWw[0]+pWw[1]+pWw[2]+pWw[3]);
    }
    gridg.sync();
  }

  // ---- Sturm bisection for lambda_max (block 0, wave 0) ----
  if (bid == 0){
    for (int i = tid; i <= LM; i += 256){
      if (i >= 1){
        sa[i] = dotWV[i];
        sb[i] = (i < LM) ? sqrt((double)betaSq[i]) : 0.0;
      }
    }
    __syncthreads();
    if (tid < 64){
      const int lane = tid;
      double phi = -1e300, plo = 1e300;
      for (int i = 1 + lane; i <= LM; i += 64){
        double r = (i > 1 ? sb[i-1] : 0.0) + (i < LM ? sb[i] : 0.0);
        phi = fmax(phi, sa[i] + r);
        plo = fmin(plo, sa[i] - r);
      }
      for (int o = 32; o > 0; o >>= 1){
        phi = fmax(phi, __shfl_down(phi, o));
        plo = fmin(plo, __shfl_down(plo, o));
      }
      double hi = __shfl(phi, 0), lo = __shfl(plo, 0);
      for (int round = 0; round < 6; round++){
        double x = lo + (hi - lo) * (double)(lane + 1) / 65.0;
        int cnt = 0;
        double dd = sa[1] - x;
        if (dd < 0) cnt++;
        for (int i = 2; i <= LM; i++){
          double off = sb[i-1];
          if (fabs(dd) < 1e-300) dd = -1e-300;
          dd = sa[i] - x - off*off/dd;
          if (dd < 0) cnt++;
        }
        unsigned long long bal = __ballot(cnt == LM);
        int p = (bal == 0ull) ? 64 : (__ffsll((unsigned long long)bal) - 1);
        double newhi = (p <= 63) ? lo + (hi - lo) * (double)(p + 1) / 65.0 : hi;
        double newlo = (p >= 1)  ? lo + (hi - lo) * (double)p / 65.0       : lo;
        hi = newhi; lo = newlo;
      }
      if (lane == 0){
        double L = 0.5*(lo + hi);
        Lbuf[0] = (float)(1.0 / L);
        Lbuf[1] = (float)(0.5 * (double)alphaIn[0] / L);
      }
    }
  }
}

// ---------------- FISTA ----------------

// iteration 0 elementwise (y0=0): sres = src*Y, delta-half update
__global__ __launch_bounds__(256) void k_A0(const float* __restrict__ Y, const float* __restrict__ src,
                                            float* __restrict__ yd, ushort_t* __restrict__ sresh,
                                            ushort_t* __restrict__ sresl, float* __restrict__ out,
                                            const float* __restrict__ Lbuf){
  int idx = blockIdx.x*256 + threadIdx.x;
  float invL = Lbuf[0], th = Lbuf[1];
  float y = Y[idx], s = src[idx];
  split2(s*y, &sresh[idx], &sresl[idx]);
  float xn = softt(y*invL, th);
  int b = idx >> 11, i = idx & 2047;
  out[(size_t)b*4096 + 2048 + i] = xn;
  yd[idx] = xn;   // c0 = 0 -> y1 = x1
}

// GEMM1: acc[b][i] = sum_k ym[b][k]*W[i][k]; fused res/sres/delta update
__global__ __launch_bounds__(256) void k_gemmA(
    const ushort_t* __restrict__ Wah, const ushort_t* __restrict__ Wal,
    const ushort_t* __restrict__ ymh, const ushort_t* __restrict__ yml,
    const float* __restrict__ Y, const float* __restrict__ src,
    float* __restrict__ yd, float* __restrict__ out,
    ushort_t* __restrict__ sresh, ushort_t* __restrict__ sresl,
    const float* __restrict__ Lbuf, float ck)
{
  f32x4 acc[2][2] = {};
  const int m0 = blockIdx.y * 64, n0 = blockIdx.x * 64;
  gemm_core(ymh, yml, Wah, Wal, m0, n0, SDIM, acc);
  const float invL = Lbuf[0], th = Lbuf[1];
  const int tid = threadIdx.x, lane = tid & 63, wv = tid >> 6;
  const int wm = (wv >> 1) * 32, wn = (wv & 1) * 32;
  const int mm = lane & 15, quad = lane >> 4;
  #pragma unroll
  for (int tm = 0; tm < 2; tm++)
    #pragma unroll
    for (int tn = 0; tn < 2; tn++)
      #pragma unroll
      for (int i = 0; i < 4; i++){
        int brow = m0 + wm + tm*16 + quad*4 + i;
        int col  = n0 + wn + tn*16 + mm;
        int g = brow*SDIM + col;
        float a = acc[tm][tn][i];
        float s = src[g], ydv = yd[g];
        float res = Y[g] - s*a - ydv;
        split2(s*res, &sresh[g], &sresl[g]);
        float xn = softt(ydv + res*invL, th);
        int go = brow*4096 + 2048 + col;
        float xo = out[go];
        out[go] = xn;
        yd[g] = xn + ck*(xn - xo);
      }
}

// GEMM2: acc[b][j] = sum_i sres[b][i]*W[i][j]; fused theta update
template<bool FIRST>
__global__ __launch_bounds__(256) void k_gemmB(
    const ushort_t* __restrict__ Wbh, const ushort_t* __restrict__ Wbl,
    const ushort_t* __restrict__ sresh, const ushort_t* __restrict__ sresl,
    ushort_t* __restrict__ ymh, ushort_t* __restrict__ yml,
    float* __restrict__ out, const float* __restrict__ Lbuf, float ck)
{
  f32x4 acc[2][2] = {};
  const int m0 = blockIdx.y * 64, n0 = blockIdx.x * 64;
  gemm_core(sresh, sresl, Wbh, Wbl, m0, n0, SDIM, acc);
  const float invL = Lbuf[0], th = Lbuf[1];
  const int tid = threadIdx.x, lane = tid & 63, wv = tid >> 6;
  const int wm = (wv >> 1) * 32, wn = (wv & 1) * 32;
  const int mm = lane & 15, quad = lane >> 4;
  #pragma unroll
  for (int tm = 0; tm < 2; tm++)
    #pragma unroll
    for (int tn = 0; tn < 2; tn++)
      #pragma unroll
      for (int i = 0; i < 4; i++){
        int brow = m0 + wm + tm*16 + quad*4 + i;
        int col  = n0 + wn + tn*16 + mm;
        int g = brow*SDIM + col;
        float a = acc[tm][tn][i];
        float ymv = FIRST ? 0.f : (bf2f(ymh[g]) + bf2f(yml[g]));
        float xn = softt(ymv + a*invL, th);
        int go = brow*4096 + col;
        float xo = FIRST ? 0.f : out[go];
        out[go] = xn;
        split2(xn + ck*(xn - xo), &ymh[g], &yml[g]);
      }
}

// ---------------- host ----------------

extern "C" void kernel_launch(void* const* d_in, const int* in_sizes, int n_in,
                              void* d_out, int out_size, void* d_ws, size_t ws_size,
                              hipStream_t stream) {
  const float* src   = (const float*)d_in[0];
  const float* Y     = (const float*)d_in[1];
  const float* W     = (const float*)d_in[2];
  const float* alpha = (const float*)d_in[3];
  float* out = (float*)d_out;
  float* ws  = (float*)d_ws;

  const size_t M1 = 1024*1024;
  float* Mmat = ws;                      // 4M floats (16MB)
  float* yd   = ws + 4*M1;               // 2M floats
  float* lanc = ws + 6*M1;
  float* w0      = lanc;                 // 2048
  float* w1      = lanc + SDIM;          // 2048
  float* vRing   = lanc + 2*SDIM;        // 3*2048
  double* dotWV  = (double*)(lanc + 5*SDIM);        // 128 doubles
  double* dotWW  = dotWV + 128;                     // 128 doubles
  float* betaSq  = lanc + 5*SDIM + 512;             // 128 floats
  float* Lbuf    = betaSq + 128;                    // 2
  ushort_t* u16 = (ushort_t*)(ws + 7*M1);
  ushort_t* Wah = u16;                   // 4M u16 each
  ushort_t* Wal = u16 + 4*M1;
  ushort_t* Wbh = u16 + 8*M1;
  ushort_t* Wbl = u16 + 12*M1;
  ushort_t* ymh = u16 + 16*M1;           // 2M u16 each
  ushort_t* yml = u16 + 18*M1;
  ushort_t* sresh = u16 + 20*M1;
  ushort_t* sresl = u16 + 22*M1;

  // ---- split W (and W^T) into bf16 hi/lo ----
  k_split<<<dim3(64,64), 256, 0, stream>>>(W, Wah, Wal, Wbh, Wbl);
  // ---- M = W W^T for Lanczos ----
  k_gemmM<<<dim3(32,32), 256, 0, stream>>>(Wah, Wal, Mmat);

  // ---- fused Lanczos (init + LM steps + Sturm) in ONE cooperative kernel ----
  {
    float* Mp = Mmat; float* w0p = w0; float* w1p = w1; float* vRp = vRing;
    double* dwvp = dotWV; double* dwwp = dotWW; float* bsp = betaSq;
    const float* alp = alpha; float* Lp = Lbuf;
    void* kargs[] = { &Mp, &w0p, &w1p, &vRp, &dwvp, &dwwp, &bsp, &alp, &Lp };
    hipLaunchCooperativeKernel((void*)k_lanczos, dim3(256), dim3(256), kargs, 0, stream);
  }

  // ---- momentum coefficients (data independent) ----
  double t = 1.0;
  float ckv[NITER];
  for (int k = 0; k < NITER; k++){
    double tn = 0.5*(1.0 + sqrt(1.0 + 4.0*t*t));
    ckv[k] = (float)((t - 1.0)/tn);
    t = tn;
  }

  // ---- FISTA ----
  k_A0<<<(BATCH*SDIM)/256, 256, 0, stream>>>(Y, src, yd, sresh, sresl, out, Lbuf);
  k_gemmB<true><<<dim3(32,16), 256, 0, stream>>>(Wbh, Wbl, sresh, sresl, ymh, yml, out, Lbuf, ckv[0]);
  for (int k = 1; k < NITER; k++){
    k_gemmA<<<dim3(32,16), 256, 0, stream>>>(Wah, Wal, ymh, yml, Y, src, yd, out, sresh, sresl, Lbuf, ckv[k]);
    k_gemmB<false><<<dim3(32,16), 256, 0, stream>>>(Wbh, Wbl, sresh, sresl, ymh, yml, out, Lbuf, ckv[k]);
  }
  (void)in_sizes; (void)n_in; (void)out_size; (void)ws_size;
}

// Round 6
// 2273.322 us; speedup vs baseline: 1.8045x; 1.8045x over previous
//
#include <hip/hip_runtime.h>
#include <math.h>

#define SDIM 2048
#define BATCH 1024
#define NITER 16
#define LM 64   // Lanczos steps

typedef unsigned short ushort_t;
typedef __attribute__((ext_vector_type(8))) short bf16x8;
typedef __attribute__((ext_vector_type(4))) float f32x4;

#define MFMA(a,b,c) __builtin_amdgcn_mfma_f32_16x16x32_bf16((a),(b),(c),0,0,0)

__device__ __forceinline__ float softt(float v, float th){
  return copysignf(fmaxf(fabsf(v) - th, 0.0f), v);
}

__device__ __forceinline__ float bf2f(ushort_t h){
  return __uint_as_float(((unsigned)h) << 16);
}

// RTNE float -> bf16 hi + bf16 lo split
__device__ __forceinline__ void split2(float x, ushort_t* h, ushort_t* l){
  unsigned u = __float_as_uint(x);
  unsigned hh = (u + 0x7FFFu + ((u >> 16) & 1u)) >> 16;
  float hf = __uint_as_float(hh << 16);
  float r = x - hf;                       // exact
  unsigned v = __float_as_uint(r);
  unsigned ll = (v + 0x7FFFu + ((v >> 16) & 1u)) >> 16;
  *h = (ushort_t)hh; *l = (ushort_t)ll;
}

// async 16B global -> LDS
__device__ __forceinline__ void cp16(const ushort_t* g, ushort_t* l){
  __builtin_amdgcn_global_load_lds(
      (const __attribute__((address_space(1))) unsigned int*)g,
      (__attribute__((address_space(3))) unsigned int*)l, 16, 0, 0);
}

// ---------------- MFMA GEMM core (64x64 tile, BK=64, 2 waves) ----------------
// C[m][n] = sum_k A[m][k]*B[n][k], A,B row-major bf16 hi/lo split.
// 128 threads = 2 waves; wave wv computes ALL 64 rows x cols wv*32..+32.
// Per kt per wave: 24 ds_read_b128 feed 48 MFMA (ratio 2.0, vs 1.5 in the
// 4-wave version) -- LDS-bound core, so fewer reads/MFMA is the lever.
// LDS layout identical to the proven r3 core (measured 0 bank conflicts):
// chunk (row r, kchunk kp of 8) at ushort offset r*64 + (kp^(r&7))*8.
// 32KB LDS/block -> 4 blocks/CU -> 8 waves/CU.
__device__ __forceinline__ void gemm_core(const ushort_t* __restrict__ Ah, const ushort_t* __restrict__ Al,
                                          const ushort_t* __restrict__ Bh, const ushort_t* __restrict__ Bl,
                                          int m0, int n0, int K, f32x4 acc[4][2])
{
  __shared__ ushort_t lAh[64*64], lAl[64*64], lBh[64*64], lBl[64*64];
  const int tid = threadIdx.x;   // 0..127
  // staging: 4 chunks per buffer per thread: c = tid + 128*i
  int soff[4], doff[4];
  #pragma unroll
  for (int i = 0; i < 4; i++){
    int c = tid + 128*i;
    int rr = c >> 3;
    int kp = (c & 7) ^ (rr & 7);
    soff[i] = rr * K + kp * 8;
    doff[i] = c * 8;
  }
  const ushort_t* gAh = Ah + (size_t)m0 * K;
  const ushort_t* gAl = Al + (size_t)m0 * K;
  const ushort_t* gBh = Bh + (size_t)n0 * K;
  const ushort_t* gBl = Bl + (size_t)n0 * K;

  const int lane = tid & 63, wv = tid >> 6;
  const int mm = lane & 15, quad = lane >> 4;
  const int wn = wv * 32;
  const int ra[4] = { mm, 16 + mm, 32 + mm, 48 + mm };
  const int rb[2] = { wn + mm, wn + 16 + mm };

  const int nk = K / 64;
  for (int kt = 0; kt < nk; kt++){
    #pragma unroll
    for (int i = 0; i < 4; i++){
      cp16(gAh + soff[i], &lAh[doff[i]]);
      cp16(gAl + soff[i], &lAl[doff[i]]);
      cp16(gBh + soff[i], &lBh[doff[i]]);
      cp16(gBl + soff[i], &lBl[doff[i]]);
    }
    gAh += 64; gAl += 64; gBh += 64; gBl += 64;
    __syncthreads();   // drains vmcnt -> staged tile visible
    #pragma unroll
    for (int u = 0; u < 2; u++){
      bf16x8 a_h[4], a_l[4], b_h[2], b_l[2];
      #pragma unroll
      for (int tm = 0; tm < 4; tm++){
        const int off = (ra[tm]*64 + (((u*4 + quad) ^ (ra[tm] & 7)) << 3));
        a_h[tm] = *(const bf16x8*)&lAh[off];
        a_l[tm] = *(const bf16x8*)&lAl[off];
      }
      #pragma unroll
      for (int tn = 0; tn < 2; tn++){
        const int off = (rb[tn]*64 + (((u*4 + quad) ^ (rb[tn] & 7)) << 3));
        b_h[tn] = *(const bf16x8*)&lBh[off];
        b_l[tn] = *(const bf16x8*)&lBl[off];
      }
      #pragma unroll
      for (int tm = 0; tm < 4; tm++)
        #pragma unroll
        for (int tn = 0; tn < 2; tn++){
          acc[tm][tn] = MFMA(a_h[tm], b_h[tn], acc[tm][tn]);
          acc[tm][tn] = MFMA(a_h[tm], b_l[tn], acc[tm][tn]);
          acc[tm][tn] = MFMA(a_l[tm], b_h[tn], acc[tm][tn]);
        }
    }
    __syncthreads();   // protect LDS before next stage
  }
}

// ---------------- W split / transpose-split ----------------
__global__ __launch_bounds__(256) void k_split(const float* __restrict__ W,
                                               ushort_t* __restrict__ Wah, ushort_t* __restrict__ Wal,
                                               ushort_t* __restrict__ Wbh, ushort_t* __restrict__ Wbl){
  __shared__ float t[32][33];
  const int i0 = blockIdx.y * 32, j0 = blockIdx.x * 32;
  const int r = threadIdx.x >> 3, c = (threadIdx.x & 7) * 4;
  const float4 v = *(const float4*)&W[(size_t)(i0 + r) * SDIM + j0 + c];
  float vv[4] = {v.x, v.y, v.z, v.w};
  ushort_t h[4], l[4];
  #pragma unroll
  for (int q = 0; q < 4; q++){ split2(vv[q], &h[q], &l[q]); t[r][c+q] = vv[q]; }
  *(ushort4*)&Wah[(size_t)(i0 + r) * SDIM + j0 + c] = make_ushort4(h[0],h[1],h[2],h[3]);
  *(ushort4*)&Wal[(size_t)(i0 + r) * SDIM + j0 + c] = make_ushort4(l[0],l[1],l[2],l[3]);
  __syncthreads();
  #pragma unroll
  for (int q = 0; q < 4; q++) split2(t[c+q][r], &h[q], &l[q]);
  *(ushort4*)&Wbh[(size_t)(j0 + r) * SDIM + i0 + c] = make_ushort4(h[0],h[1],h[2],h[3]);
  *(ushort4*)&Wbl[(size_t)(j0 + r) * SDIM + i0 + c] = make_ushort4(l[0],l[1],l[2],l[3]);
}

// M = W * W^T (same nonzero spectrum as W^T W)
__global__ __launch_bounds__(128) void k_gemmM(const ushort_t* __restrict__ Wah, const ushort_t* __restrict__ Wal,
                                               float* __restrict__ Mmat){
  f32x4 acc[4][2] = {};
  const int m0 = blockIdx.y * 64, n0 = blockIdx.x * 64;
  gemm_core(Wah, Wal, Wah, Wal, m0, n0, SDIM, acc);
  const int tid = threadIdx.x, lane = tid & 63, wv = tid >> 6;
  const int mm = lane & 15, quad = lane >> 4;
  #pragma unroll
  for (int tm = 0; tm < 4; tm++)
    #pragma unroll
    for (int tn = 0; tn < 2; tn++)
      #pragma unroll
      for (int i = 0; i < 4; i++){
        int row = m0 + tm*16 + quad*4 + i;
        int col = n0 + wv*32 + tn*16 + mm;
        Mmat[(size_t)row * SDIM + col] = acc[tm][tn][i];
      }
}

// ---------------- Lanczos on M: one kernel per step ----------------
__global__ __launch_bounds__(256) void k_init(float* __restrict__ vRing,
                                              double* __restrict__ dotWV, double* __restrict__ dotWW,
                                              float* __restrict__ betaSq){
  __shared__ float red[256];
  int t = threadIdx.x;
  float vals[8];
  float s = 0.f;
  #pragma unroll
  for (int p = 0; p < 8; p++){
    int j = p*256 + t;
    unsigned h = (unsigned)j * 2654435761u;
    h ^= h >> 16; h *= 2246822519u; h ^= h >> 13;
    float r = (float)(h & 0xFFFFFFu) / 16777216.0f - 0.5f;
    vals[p] = r; s += r*r;
  }
  red[t] = s; __syncthreads();
  for (int o = 128; o > 0; o >>= 1){ if (t < o) red[t] += red[t+o]; __syncthreads(); }
  float inv = rsqrtf(red[0]);
  #pragma unroll
  for (int p = 0; p < 8; p++){
    int j = p*256 + t;
    vRing[SDIM + j] = vals[p]*inv;   // slot 1 = v_1
    vRing[j] = 0.f;                  // slot 0
    vRing[2*SDIM + j] = 0.f;         // slot 2
  }
  if (t < LM+2){ dotWV[t] = 0.0; dotWW[t] = 0.0; betaSq[t] = 0.f; }
}

// step s: reconstruct v_s from w_{s-1} (redundant per block), then 4 rows of M v_s.
// beta^2_{s-1} = ||w||^2 - alpha^2 - beta^2_{s-2}  (fp64 scalar chain)
__global__ __launch_bounds__(256) void k_lstep(const float* __restrict__ M,
    const float* __restrict__ wOld, float* __restrict__ wNew,
    float* __restrict__ vRing, double* __restrict__ dotWV, double* __restrict__ dotWW,
    float* __restrict__ betaSq, int s){
  __shared__ float vs[SDIM];
  __shared__ double pAl[4], pWw[4];
  const int tid = threadIdx.x, bid = blockIdx.x;
  if (s == 1){
    const float* v1 = vRing + SDIM;
    for (int j = tid; j < SDIM; j += 256) vs[j] = v1[j];
  } else {
    const double a  = dotWV[s-1];
    const double ww = dotWW[s-1];
    const float bpSq = betaSq[s-2];
    float bsq = (float)(ww - a*a - (double)bpSq);
    bsq = fmaxf(bsq, 1e-20f);
    const float beta = sqrtf(bsq), invb = 1.0f/beta;
    const float alpha = (float)a, bprev = sqrtf(bpSq);
    const float* vm1 = vRing + ((s-1)%3)*SDIM;
    const float* vm2 = vRing + ((s-2)%3)*SDIM;
    float* vdst = vRing + (s%3)*SDIM;
    for (int j = tid; j < SDIM; j += 256){
      float val = (wOld[j] - alpha*vm1[j] - bprev*vm2[j]) * invb;
      vs[j] = val;
      if (bid == 0) vdst[j] = val;
    }
    if (bid == 0 && tid == 0) betaSq[s-1] = bsq;
  }
  __syncthreads();
  const int wv = tid >> 6, lane = tid & 63;
  const int row = bid*4 + wv;
  const float4* Mr = (const float4*)(M + (size_t)row * SDIM);
  const float4* v4 = (const float4*)vs;
  float acc = 0.f;
  #pragma unroll
  for (int p = 0; p < 8; p++){
    int j4 = p*64 + lane;
    float4 m = Mr[j4], v = v4[j4];
    acc += m.x*v.x + m.y*v.y + m.z*v.z + m.w*v.w;
  }
  #pragma unroll
  for (int o = 32; o > 0; o >>= 1) acc += __shfl_down(acc, o);
  if (lane == 0){
    wNew[row] = acc;
    pAl[wv] = (double)acc * (double)vs[row];
    pWw[wv] = (double)acc * (double)acc;
  }
  __syncthreads();
  if (tid == 0){
    atomicAdd(&dotWV[s], pAl[0]+pAl[1]+pAl[2]+pAl[3]);
    atomicAdd(&dotWW[s], pWw[0]+pWw[1]+pWw[2]+pWw[3]);
  }
}

// lambda_max of tridiagonal via lane-parallel Sturm bisection (fp64)
__global__ void k_sturm(const double* __restrict__ dotWV, const float* __restrict__ betaSq,
                        const float* __restrict__ alphaIn, float* __restrict__ Lbuf){
  __shared__ double sa[LM+1], sb[LM+1];
  int lane = threadIdx.x;
  for (int i = lane; i <= LM; i += 64){
    if (i >= 1){
      sa[i] = dotWV[i];
      sb[i] = (i < LM) ? sqrt((double)betaSq[i]) : 0.0;
    }
  }
  __syncthreads();
  double phi = -1e300, plo = 1e300;
  for (int i = 1 + lane; i <= LM; i += 64){
    double r = (i > 1 ? sb[i-1] : 0.0) + (i < LM ? sb[i] : 0.0);
    phi = fmax(phi, sa[i] + r);
    plo = fmin(plo, sa[i] - r);
  }
  for (int o = 32; o > 0; o >>= 1){
    phi = fmax(phi, __shfl_down(phi, o));
    plo = fmin(plo, __shfl_down(plo, o));
  }
  double hi = __shfl(phi, 0), lo = __shfl(plo, 0);
  for (int round = 0; round < 6; round++){
    double x = lo + (hi - lo) * (double)(lane + 1) / 65.0;
    int cnt = 0;
    double dd = sa[1] - x;
    if (dd < 0) cnt++;
    for (int i = 2; i <= LM; i++){
      double off = sb[i-1];
      if (fabs(dd) < 1e-300) dd = -1e-300;
      dd = sa[i] - x - off*off/dd;
      if (dd < 0) cnt++;
    }
    unsigned long long bal = __ballot(cnt == LM);
    int p = (bal == 0ull) ? 64 : (__ffsll((unsigned long long)bal) - 1);
    double newhi = (p <= 63) ? lo + (hi - lo) * (double)(p + 1) / 65.0 : hi;
    double newlo = (p >= 1)  ? lo + (hi - lo) * (double)p / 65.0       : lo;
    hi = newhi; lo = newlo;
  }
  if (lane == 0){
    double L = 0.5*(lo + hi);
    Lbuf[0] = (float)(1.0 / L);
    Lbuf[1] = (float)(0.5 * (double)alphaIn[0] / L);
  }
}

// ---------------- FISTA ----------------

// iteration 0 elementwise (y0=0): sres = src*Y, delta-half update
__global__ __launch_bounds__(256) void k_A0(const float* __restrict__ Y, const float* __restrict__ src,
                                            float* __restrict__ yd, ushort_t* __restrict__ sresh,
                                            ushort_t* __restrict__ sresl, float* __restrict__ out,
                                            const float* __restrict__ Lbuf){
  int idx = blockIdx.x*256 + threadIdx.x;
  float invL = Lbuf[0], th = Lbuf[1];
  float y = Y[idx], s = src[idx];
  split2(s*y, &sresh[idx], &sresl[idx]);
  float xn = softt(y*invL, th);
  int b = idx >> 11, i = idx & 2047;
  out[(size_t)b*4096 + 2048 + i] = xn;
  yd[idx] = xn;   // c0 = 0 -> y1 = x1
}

// GEMM1: acc[b][i] = sum_k ym[b][k]*W[i][k]; fused res/sres/delta update
__global__ __launch_bounds__(128) void k_gemmA(
    const ushort_t* __restrict__ Wah, const ushort_t* __restrict__ Wal,
    const ushort_t* __restrict__ ymh, const ushort_t* __restrict__ yml,
    const float* __restrict__ Y, const float* __restrict__ src,
    float* __restrict__ yd, float* __restrict__ out,
    ushort_t* __restrict__ sresh, ushort_t* __restrict__ sresl,
    const float* __restrict__ Lbuf, float ck)
{
  f32x4 acc[4][2] = {};
  const int m0 = blockIdx.y * 64, n0 = blockIdx.x * 64;
  gemm_core(ymh, yml, Wah, Wal, m0, n0, SDIM, acc);
  const float invL = Lbuf[0], th = Lbuf[1];
  const int tid = threadIdx.x, lane = tid & 63, wv = tid >> 6;
  const int mm = lane & 15, quad = lane >> 4;
  #pragma unroll
  for (int tm = 0; tm < 4; tm++)
    #pragma unroll
    for (int tn = 0; tn < 2; tn++)
      #pragma unroll
      for (int i = 0; i < 4; i++){
        int brow = m0 + tm*16 + quad*4 + i;
        int col  = n0 + wv*32 + tn*16 + mm;
        int g = brow*SDIM + col;
        float a = acc[tm][tn][i];
        float s = src[g], ydv = yd[g];
        float res = Y[g] - s*a - ydv;
        split2(s*res, &sresh[g], &sresl[g]);
        float xn = softt(ydv + res*invL, th);
        int go = brow*4096 + 2048 + col;
        float xo = out[go];
        out[go] = xn;
        yd[g] = xn + ck*(xn - xo);
      }
}

// GEMM2: acc[b][j] = sum_i sres[b][i]*W[i][j]; fused theta update
template<bool FIRST>
__global__ __launch_bounds__(128) void k_gemmB(
    const ushort_t* __restrict__ Wbh, const ushort_t* __restrict__ Wbl,
    const ushort_t* __restrict__ sresh, const ushort_t* __restrict__ sresl,
    ushort_t* __restrict__ ymh, ushort_t* __restrict__ yml,
    float* __restrict__ out, const float* __restrict__ Lbuf, float ck)
{
  f32x4 acc[4][2] = {};
  const int m0 = blockIdx.y * 64, n0 = blockIdx.x * 64;
  gemm_core(sresh, sresl, Wbh, Wbl, m0, n0, SDIM, acc);
  const float invL = Lbuf[0], th = Lbuf[1];
  const int tid = threadIdx.x, lane = tid & 63, wv = tid >> 6;
  const int mm = lane & 15, quad = lane >> 4;
  #pragma unroll
  for (int tm = 0; tm < 4; tm++)
    #pragma unroll
    for (int tn = 0; tn < 2; tn++)
      #pragma unroll
      for (int i = 0; i < 4; i++){
        int brow = m0 + tm*16 + quad*4 + i;
        int col  = n0 + wv*32 + tn*16 + mm;
        int g = brow*SDIM + col;
        float a = acc[tm][tn][i];
        float ymv = FIRST ? 0.f : (bf2f(ymh[g]) + bf2f(yml[g]));
        float xn = softt(ymv + a*invL, th);
        int go = brow*4096 + col;
        float xo = FIRST ? 0.f : out[go];
        out[go] = xn;
        split2(xn + ck*(xn - xo), &ymh[g], &yml[g]);
      }
}

// ---------------- host ----------------

extern "C" void kernel_launch(void* const* d_in, const int* in_sizes, int n_in,
                              void* d_out, int out_size, void* d_ws, size_t ws_size,
                              hipStream_t stream) {
  const float* src   = (const float*)d_in[0];
  const float* Y     = (const float*)d_in[1];
  const float* W     = (const float*)d_in[2];
  const float* alpha = (const float*)d_in[3];
  float* out = (float*)d_out;
  float* ws  = (float*)d_ws;

  const size_t M1 = 1024*1024;
  float* Mmat = ws;                      // 4M floats (16MB)
  float* yd   = ws + 4*M1;               // 2M floats
  float* lanc = ws + 6*M1;
  float* w0      = lanc;                 // 2048
  float* w1      = lanc + SDIM;          // 2048
  float* vRing   = lanc + 2*SDIM;        // 3*2048
  double* dotWV  = (double*)(lanc + 5*SDIM);        // 128 doubles
  double* dotWW  = dotWV + 128;                     // 128 doubles
  float* betaSq  = lanc + 5*SDIM + 512;             // 128 floats
  float* Lbuf    = betaSq + 128;                    // 2
  ushort_t* u16 = (ushort_t*)(ws + 7*M1);
  ushort_t* Wah = u16;                   // 4M u16 each
  ushort_t* Wal = u16 + 4*M1;
  ushort_t* Wbh = u16 + 8*M1;
  ushort_t* Wbl = u16 + 12*M1;
  ushort_t* ymh = u16 + 16*M1;           // 2M u16 each
  ushort_t* yml = u16 + 18*M1;
  ushort_t* sresh = u16 + 20*M1;
  ushort_t* sresl = u16 + 22*M1;

  // ---- split W (and W^T) into bf16 hi/lo ----
  k_split<<<dim3(64,64), 256, 0, stream>>>(W, Wah, Wal, Wbh, Wbl);
  // ---- M = W W^T for Lanczos ----
  k_gemmM<<<dim3(32,32), 128, 0, stream>>>(Wah, Wal, Mmat);

  // ---- Lanczos for L = lambda_max: one kernel per step ----
  float* wb[2] = { w0, w1 };
  k_init<<<1, 256, 0, stream>>>(vRing, dotWV, dotWW, betaSq);
  for (int s = 1; s <= LM; s++){
    k_lstep<<<512, 256, 0, stream>>>(Mmat, wb[(s+1)&1], wb[s&1], vRing, dotWV, dotWW, betaSq, s);
  }
  k_sturm<<<1, 64, 0, stream>>>(dotWV, betaSq, alpha, Lbuf);

  // ---- momentum coefficients (data independent) ----
  double t = 1.0;
  float ckv[NITER];
  for (int k = 0; k < NITER; k++){
    double tn = 0.5*(1.0 + sqrt(1.0 + 4.0*t*t));
    ckv[k] = (float)((t - 1.0)/tn);
    t = tn;
  }

  // ---- FISTA ----
  k_A0<<<(BATCH*SDIM)/256, 256, 0, stream>>>(Y, src, yd, sresh, sresl, out, Lbuf);
  k_gemmB<true><<<dim3(32,16), 128, 0, stream>>>(Wbh, Wbl, sresh, sresl, ymh, yml, out, Lbuf, ckv[0]);
  for (int k = 1; k < NITER; k++){
    k_gemmA<<<dim3(32,16), 128, 0, stream>>>(Wah, Wal, ymh, yml, Y, src, yd, out, sresh, sresl, Lbuf, ckv[k]);
    k_gemmB<false><<<dim3(32,16), 128, 0, stream>>>(Wbh, Wbl, sresh, sresl, ymh, yml, out, Lbuf, ckv[k]);
  }
  (void)in_sizes; (void)n_in; (void)out_size; (void)ws_size;
}